// Round 3
// baseline (1494.593 us; speedup 1.0000x reference)
//
#include <hip/hip_runtime.h>
#include <hip/hip_bf16.h>
#include <hip/hip_fp16.h>

#define OC_N     2048
#define IC_N     2048
#define RC       6144      // rows = OC_N*3, cols = IC_N*3
#define OCSTRIDE 18432     // IC_N*9 floats per oc slice
#define UNSCALE  0.0000152587890625f   // 2^-16 cancels the fp8 256x encode scale per iter
#define NBLK     768       // persistent grid: 3 blocks/CU x 256 CUs

typedef float v2f __attribute__((ext_vector_type(2)));

__device__ __forceinline__ float wave_reduce(float x) {
#pragma unroll
    for (int off = 32; off > 0; off >>= 1) x += __shfl_down(x, off, 64);
    return x;
}

// ---------------------------------------------------------------------------
// Wq[r][c] = fp8_e4m3(256 * conv[oc][ic][hh][ww]), r=oc*3+hh, c=ic*3+ww.
// Thread writes 8 consecutive fp8 (8B store, coalesced). 18432 blocks.
// Block 0 additionally zeroes the grid-barrier flags (runs before power_iter
// in stream order each graph replay, so barrier state is always clean).
__global__ __launch_bounds__(256) void convert_q_kernel(
    const float* __restrict__ conv, unsigned char* __restrict__ Wq,
    int* __restrict__ flags)
{
    if (blockIdx.x == 0) {
        for (int k = threadIdx.x; k < NBLK + 1; k += 256) flags[k] = 0;
    }
    const int t  = blockIdx.x * 256 + threadIdx.x;
    const int o8 = t * 8;                       // < 2^26, fits int
    const int r  = o8 / RC;
    const int c0 = o8 % RC;
    const int oc = r / 3, hh = r % 3;
    const float* base = conv + (size_t)oc * OCSTRIDE + hh * 3;
    float f[8];
#pragma unroll
    for (int e = 0; e < 8; ++e) {
        const int c  = c0 + e;
        const int ic = c / 3, ww = c - 3 * ic;
        f[e] = base[ic * 9 + ww] * 256.0f;
    }
    int lo = __builtin_amdgcn_cvt_pk_fp8_f32(f[0], f[1], 0, false);
    lo     = __builtin_amdgcn_cvt_pk_fp8_f32(f[2], f[3], lo, true);
    int hi = __builtin_amdgcn_cvt_pk_fp8_f32(f[4], f[5], 0, false);
    hi     = __builtin_amdgcn_cvt_pk_fp8_f32(f[6], f[7], hi, true);
    *reinterpret_cast<uint2*>(Wq + o8) = make_uint2((unsigned)lo, (unsigned)hi);
}

// ---------------------------------------------------------------------------
// WqT[c][r] = Wq[r][c]  — 64x64 byte tiles via LDS. Grid (96, 96), 256 thr.
__global__ __launch_bounds__(256) void transpose_q_kernel(
    const unsigned char* __restrict__ Wq, unsigned char* __restrict__ WqT)
{
    __shared__ unsigned char tile[64][68];
    const int tid = threadIdx.x;
    const int tr  = blockIdx.x;          // row tile of Wq
    const int tc  = blockIdx.y;          // col tile of Wq

    const int r  = tid >> 2;
    const int cq = (tid & 3) * 16;
    const uint4 w = *reinterpret_cast<const uint4*>(
        Wq + (size_t)(tr * 64 + r) * RC + tc * 64 + cq);
    *reinterpret_cast<unsigned int*>(&tile[r][cq +  0]) = w.x;
    *reinterpret_cast<unsigned int*>(&tile[r][cq +  4]) = w.y;
    *reinterpret_cast<unsigned int*>(&tile[r][cq +  8]) = w.z;
    *reinterpret_cast<unsigned int*>(&tile[r][cq + 12]) = w.w;
    __syncthreads();

    const int orow = tid >> 2;
    const int ocq  = (tid & 3) * 16;
    unsigned int u32s[4];
#pragma unroll
    for (int wi = 0; wi < 4; ++wi) {
        const int ro = ocq + 4 * wi;
        u32s[wi] =  (unsigned int)tile[ro + 0][orow]
                 | ((unsigned int)tile[ro + 1][orow] << 8)
                 | ((unsigned int)tile[ro + 2][orow] << 16)
                 | ((unsigned int)tile[ro + 3][orow] << 24);
    }
    uint4 o = make_uint4(u32s[0], u32s[1], u32s[2], u32s[3]);
    *reinterpret_cast<uint4*>(WqT + (size_t)(tc * 64 + orow) * RC + tr * 64 + ocq) = o;
}

// ---------------------------------------------------------------------------
// 16-element fp8 dot: w holds 16 fp8, a..d hold the 16 matching f32 x-values.
__device__ __forceinline__ float dot16(uint4 w, float4 a, float4 b, float4 c, float4 d) {
    float acc = 0.f;
    v2f f;
    f = __builtin_amdgcn_cvt_pk_f32_fp8(w.x, false); acc += f.x * a.x + f.y * a.y;
    f = __builtin_amdgcn_cvt_pk_f32_fp8(w.x, true);  acc += f.x * a.z + f.y * a.w;
    f = __builtin_amdgcn_cvt_pk_f32_fp8(w.y, false); acc += f.x * b.x + f.y * b.y;
    f = __builtin_amdgcn_cvt_pk_f32_fp8(w.y, true);  acc += f.x * b.z + f.y * b.w;
    f = __builtin_amdgcn_cvt_pk_f32_fp8(w.z, false); acc += f.x * c.x + f.y * c.y;
    f = __builtin_amdgcn_cvt_pk_f32_fp8(w.z, true);  acc += f.x * c.z + f.y * c.w;
    f = __builtin_amdgcn_cvt_pk_f32_fp8(w.w, false); acc += f.x * d.x + f.y * d.y;
    f = __builtin_amdgcn_cvt_pk_f32_fp8(w.w, true);  acc += f.x * d.z + f.y * d.w;
    return acc;
}

// Stage the 6144-float x vector into padded LDS (+1 float4 slot per 4):
// lane byte-stride 80 -> bank stride 20; conflict-free ds_read_b128.
__device__ __forceinline__ void stage_x(const float* __restrict__ x,
                                        float4* __restrict__ x4, int tid) {
    const float4* s4 = reinterpret_cast<const float4*>(x);
#pragma unroll
    for (int k = 0; k < 6; ++k) {
        const int g = tid + 256 * k;              // logical float4 index
        x4[g + (g >> 2)] = s4[g];                 // padded slot
    }
}

// Two rows of W dot x (x in padded LDS). uint4 (16B) weight loads.
__device__ __forceinline__ void matvec_rows2(
    const unsigned char* __restrict__ W, const float4* __restrict__ x4,
    int rbase, int lane, float* out0, float* out1)
{
    const unsigned char* w0 = W + (size_t)rbase * RC;
    float acc0 = 0.f, acc1 = 0.f;
#pragma unroll
    for (int i = 0; i < 6; ++i) {
        const int slot = i * 320 + lane * 5;      // padded float4 slot
        const float4 a = x4[slot + 0];
        const float4 b = x4[slot + 1];
        const float4 c = x4[slot + 2];
        const float4 d = x4[slot + 3];
        const uint4 wA = *reinterpret_cast<const uint4*>(w0 +      i * 1024 + lane * 16);
        const uint4 wB = *reinterpret_cast<const uint4*>(w0 + RC + i * 1024 + lane * 16);
        acc0 += dot16(wA, a, b, c, d);
        acc1 += dot16(wB, a, b, c, d);
    }
    *out0 = wave_reduce(acc0);
    *out1 = wave_reduce(acc1);
}

// ---------------------------------------------------------------------------
// Software grid barrier for a fully-resident 768-block grid.
// Arrival: threadfence (buffer_wbl2, publishes this block's v/u writes) +
// flag store. Block 0 wave 0 polls all flags wave-parallel (12/lane, relaxed
// coherent loads), then publishes gen. Departure: acquire fence (buffer_inv)
// so stale v/u lines are dropped before the next staging reads.
__device__ __forceinline__ void grid_barrier(int* __restrict__ flags,
                                             int* __restrict__ gen,
                                             int bid, int tid, int g)
{
    __syncthreads();
    if (tid == 0) {
        __threadfence();
        __hip_atomic_store(&flags[bid], g, __ATOMIC_RELAXED, __HIP_MEMORY_SCOPE_AGENT);
    }
    if (bid == 0 && tid < 64) {
        const int base = tid * 12;                // 64 lanes x 12 = 768 flags
        for (;;) {
            bool ok = true;
#pragma unroll
            for (int k = 0; k < 12; ++k)
                ok &= (__hip_atomic_load(&flags[base + k], __ATOMIC_RELAXED,
                                         __HIP_MEMORY_SCOPE_AGENT) >= g);
            if (__all(ok)) break;
            __builtin_amdgcn_s_sleep(1);
        }
        if (tid == 0)
            __hip_atomic_store(gen, g, __ATOMIC_RELAXED, __HIP_MEMORY_SCOPE_AGENT);
    }
    if (tid == 0) {
        while (__hip_atomic_load(gen, __ATOMIC_RELAXED, __HIP_MEMORY_SCOPE_AGENT) < g)
            __builtin_amdgcn_s_sleep(1);
        __builtin_amdgcn_fence(__ATOMIC_ACQUIRE, "agent");
    }
    __syncthreads();
}

// ---------------------------------------------------------------------------
// All 10 power iterations in ONE persistent kernel. 768 blocks x 256 thr;
// __launch_bounds__(256,3) guarantees 3 blocks/CU capacity -> all 768
// co-resident (LDS 30KB*3=90KB<160KB, VGPR capped by bound). Regular launch,
// graph-capture safe. 19 grid barriers replace 19 kernel transitions.
__global__ __launch_bounds__(256, 3) void power_iter_kernel(
    const unsigned char* __restrict__ Wq, const unsigned char* __restrict__ WqT,
    const float* __restrict__ u_in, float* __restrict__ u_vec,
    float* __restrict__ v_vec, int* __restrict__ flags)
{
    __shared__ float x_lds[7680];                 // 6144 + 1536 pad floats
    float4* x4 = reinterpret_cast<float4*>(x_lds);
    int* gen = flags + NBLK;

    const int tid   = threadIdx.x;
    const int lane  = tid & 63;
    const int wid   = tid >> 6;
    const int bid   = blockIdx.x;
    const int rbase = bid * 8 + wid * 2;
    int g = 0;

    for (int it = 0; it < 10; ++it) {
        // ---- phase V: v = Wq * u ----
        stage_x(it == 0 ? u_in : u_vec, x4, tid);
        __syncthreads();
        float a0, a1;
        matvec_rows2(Wq, x4, rbase, lane, &a0, &a1);
        if (lane == 0) { v_vec[rbase] = a0; v_vec[rbase + 1] = a1; }
        ++g; grid_barrier(flags, gen, bid, tid, g);

        // ---- phase U: u = WqT * v * 2^-16 ----
        stage_x(v_vec, x4, tid);
        __syncthreads();
        matvec_rows2(WqT, x4, rbase, lane, &a0, &a1);
        if (lane == 0) { u_vec[rbase] = a0 * UNSCALE; u_vec[rbase + 1] = a1 * UNSCALE; }
        if (it != 9) { ++g; grid_barrier(flags, gen, bid, tid, g); }
    }
}

// ---------------------------------------------------------------------------
// Final fp32 pass on ORIGINAL conv: t = W * (u/||u||). One block per oc.
__global__ __launch_bounds__(256) void vstep_kernel(
    const float* __restrict__ conv, const float* __restrict__ u,
    float* __restrict__ v_out)
{
    __shared__ float u_lds[RC];
    __shared__ float sred[8];
    __shared__ float sred3[12];
    __shared__ float sbcast;

    const int tid  = threadIdx.x;
    const int oc   = blockIdx.x;
    const int lane = tid & 63;
    const int wid  = tid >> 6;

    float sq = 0.f;
    const float4* u4  = reinterpret_cast<const float4*>(u);
    float4*       ul4 = reinterpret_cast<float4*>(u_lds);
#pragma unroll
    for (int k = 0; k < 6; ++k) {
        float4 q = u4[tid + 256 * k];
        ul4[tid + 256 * k] = q;
        sq += q.x * q.x + q.y * q.y + q.z * q.z + q.w * q.w;
    }
    float wsum = wave_reduce(sq);
    if (lane == 0) sred[wid] = wsum;
    __syncthreads();
    if (tid == 0) sbcast = rsqrtf(sred[0] + sred[1] + sred[2] + sred[3]);
    __syncthreads();
    const float scale = sbcast;

    float acc0 = 0.f, acc1 = 0.f, acc2 = 0.f;
    const float* base = conv + (size_t)oc * OCSTRIDE;
#pragma unroll
    for (int gi = 0; gi < 2; ++gi) {
        const int g = tid + 256 * gi;
        const float4* p4  = reinterpret_cast<const float4*>(base + g * 36);
        const float4* q12 = reinterpret_cast<const float4*>(u_lds + 12 * g);
        float uv[12];
#pragma unroll
        for (int k = 0; k < 3; ++k) {
            float4 q = q12[k];
            uv[4 * k] = q.x; uv[4 * k + 1] = q.y; uv[4 * k + 2] = q.z; uv[4 * k + 3] = q.w;
        }
#pragma unroll
        for (int j = 0; j < 9; ++j) {
            float4 q = p4[j];
            float el[4] = {q.x, q.y, q.z, q.w};
#pragma unroll
            for (int e = 0; e < 4; ++e) {
                const int m   = 4 * j + e;
                const int icl = m / 9;
                const int rem = m - 9 * icl;
                const int hh  = rem / 3;
                const int ww  = rem - 3 * hh;
                const float pv = el[e] * uv[icl * 3 + ww];
                if (hh == 0) acc0 += pv;
                else if (hh == 1) acc1 += pv;
                else acc2 += pv;
            }
        }
    }
    acc0 = wave_reduce(acc0);
    acc1 = wave_reduce(acc1);
    acc2 = wave_reduce(acc2);
    if (lane == 0) { sred3[wid] = acc0; sred3[4 + wid] = acc1; sred3[8 + wid] = acc2; }
    __syncthreads();
    if (tid < 3) {
        const float s = sred3[tid * 4 + 0] + sred3[tid * 4 + 1] +
                        sred3[tid * 4 + 2] + sred3[tid * 4 + 3];
        v_out[oc * 3 + tid] = scale * s;
    }
}

// out = 3 * dot(v,t) / ||v||   (v unnormalized iterate, t = W u_hat)
__global__ __launch_bounds__(256) void final_kernel(
    const float* __restrict__ v, const float* __restrict__ t,
    float* __restrict__ out)
{
    __shared__ float ssq[4];
    __shared__ float sdot[4];
    const int tid  = threadIdx.x;
    const int lane = tid & 63;
    const int wid  = tid >> 6;
    float sq = 0.f, dot = 0.f;
#pragma unroll
    for (int k = 0; k < 24; ++k) {
        float x = v[tid + 256 * k];
        float y = t[tid + 256 * k];
        sq  += x * x;
        dot += x * y;
    }
    sq  = wave_reduce(sq);
    dot = wave_reduce(dot);
    if (lane == 0) { ssq[wid] = sq; sdot[wid] = dot; }
    __syncthreads();
    if (tid == 0) {
        const float sqt  = ssq[0] + ssq[1] + ssq[2] + ssq[3];
        const float dott = sdot[0] + sdot[1] + sdot[2] + sdot[3];
        out[0] = 3.0f * dott * rsqrtf(sqt);
    }
}

extern "C" void kernel_launch(void* const* d_in, const int* in_sizes, int n_in,
                              void* d_out, int out_size, void* d_ws, size_t ws_size,
                              hipStream_t stream)
{
    const float* conv = (const float*)d_in[0];   // [2048,2048,3,3] fp32
    const float* u_in = (const float*)d_in[1];   // [1,6144] fp32, unit norm
    float* out = (float*)d_out;

    // ws layout: Wq fp8[6144^2] | WqT fp8[6144^2] | v_vec[6144] | u_vec[6144]
    //            | t_vec[6144] floats | flags[769] ints
    const size_t WQ_BYTES = (size_t)RC * RC;                     // 37.75 MB
    const size_t needed = 2 * WQ_BYTES + (size_t)3 * RC * sizeof(float)
                        + (NBLK + 1) * sizeof(int);
    if (ws_size < needed) return;

    unsigned char* Wq  = (unsigned char*)d_ws;
    unsigned char* WqT = Wq + WQ_BYTES;
    float* v_vec = (float*)(WqT + WQ_BYTES);
    float* u_vec = v_vec + RC;
    float* t_vec = u_vec + RC;
    int*   flags = (int*)(t_vec + RC);

    convert_q_kernel<<<RC * RC / 8 / 256, 256, 0, stream>>>(conv, Wq, flags);
    transpose_q_kernel<<<dim3(RC / 64, RC / 64), 256, 0, stream>>>(Wq, WqT);
    power_iter_kernel<<<NBLK, 256, 0, stream>>>(Wq, WqT, u_in, u_vec, v_vec, flags);

    // sigma in full fp32 from original data
    vstep_kernel<<<OC_N, 256, 0, stream>>>(conv, u_vec, t_vec);
    final_kernel<<<1, 256, 0, stream>>>(v_vec, t_vec, out);
}

// Round 4
// 1305.654 us; speedup vs baseline: 1.1447x; 1.1447x over previous
//
#include <hip/hip_runtime.h>
#include <hip/hip_bf16.h>
#include <hip/hip_fp16.h>

#define OC_N     2048
#define IC_N     2048
#define RC       6144      // rows = OC_N*3, cols = IC_N*3
#define OCSTRIDE 18432     // IC_N*9 floats per oc slice
#define UNSCALE  0.0000152587890625f   // 2^-16 cancels the fp8 256x encode scale per iter
#define NBLK     768       // persistent grid: 3 blocks/CU x 256 CUs

typedef float v2f __attribute__((ext_vector_type(2)));

__device__ __forceinline__ float wave_reduce(float x) {
#pragma unroll
    for (int off = 32; off > 0; off >>= 1) x += __shfl_down(x, off, 64);
    return x;
}

// Coherent (cross-XCD) scalar access: sc0 sc1, bypasses L1/L2, NO cache fences.
__device__ __forceinline__ void cstore(float* p, float x) {
    __hip_atomic_store(p, x, __ATOMIC_RELAXED, __HIP_MEMORY_SCOPE_AGENT);
}
__device__ __forceinline__ float cload(const float* p) {
    return __hip_atomic_load(const_cast<float*>(p), __ATOMIC_RELAXED,
                             __HIP_MEMORY_SCOPE_AGENT);
}
__device__ __forceinline__ void cstore_i(int* p, int x) {
    __hip_atomic_store(p, x, __ATOMIC_RELAXED, __HIP_MEMORY_SCOPE_AGENT);
}
__device__ __forceinline__ int cload_i(const int* p) {
    return __hip_atomic_load(const_cast<int*>(p), __ATOMIC_RELAXED,
                             __HIP_MEMORY_SCOPE_AGENT);
}

// ---------------------------------------------------------------------------
// Wq[r][c] = fp8_e4m3(256 * conv[oc][ic][hh][ww]), r=oc*3+hh, c=ic*3+ww.
// Block 0 zeroes the grid-barrier flags with COHERENT stores (so no stale
// flag lines can exist in any XCD's L2 at power_iter start).
__global__ __launch_bounds__(256) void convert_q_kernel(
    const float* __restrict__ conv, unsigned char* __restrict__ Wq,
    int* __restrict__ flags)
{
    if (blockIdx.x == 0) {
        for (int k = threadIdx.x; k < NBLK + 1; k += 256) cstore_i(&flags[k], 0);
    }
    const int t  = blockIdx.x * 256 + threadIdx.x;
    const int o8 = t * 8;                       // < 2^26, fits int
    const int r  = o8 / RC;
    const int c0 = o8 % RC;
    const int oc = r / 3, hh = r % 3;
    const float* base = conv + (size_t)oc * OCSTRIDE + hh * 3;
    float f[8];
#pragma unroll
    for (int e = 0; e < 8; ++e) {
        const int c  = c0 + e;
        const int ic = c / 3, ww = c - 3 * ic;
        f[e] = base[ic * 9 + ww] * 256.0f;
    }
    int lo = __builtin_amdgcn_cvt_pk_fp8_f32(f[0], f[1], 0, false);
    lo     = __builtin_amdgcn_cvt_pk_fp8_f32(f[2], f[3], lo, true);
    int hi = __builtin_amdgcn_cvt_pk_fp8_f32(f[4], f[5], 0, false);
    hi     = __builtin_amdgcn_cvt_pk_fp8_f32(f[6], f[7], hi, true);
    *reinterpret_cast<uint2*>(Wq + o8) = make_uint2((unsigned)lo, (unsigned)hi);
}

// ---------------------------------------------------------------------------
// WqT[c][r] = Wq[r][c]  — 64x64 byte tiles via LDS. Grid (96, 96), 256 thr.
__global__ __launch_bounds__(256) void transpose_q_kernel(
    const unsigned char* __restrict__ Wq, unsigned char* __restrict__ WqT)
{
    __shared__ unsigned char tile[64][68];
    const int tid = threadIdx.x;
    const int tr  = blockIdx.x;          // row tile of Wq
    const int tc  = blockIdx.y;          // col tile of Wq

    const int r  = tid >> 2;
    const int cq = (tid & 3) * 16;
    const uint4 w = *reinterpret_cast<const uint4*>(
        Wq + (size_t)(tr * 64 + r) * RC + tc * 64 + cq);
    *reinterpret_cast<unsigned int*>(&tile[r][cq +  0]) = w.x;
    *reinterpret_cast<unsigned int*>(&tile[r][cq +  4]) = w.y;
    *reinterpret_cast<unsigned int*>(&tile[r][cq +  8]) = w.z;
    *reinterpret_cast<unsigned int*>(&tile[r][cq + 12]) = w.w;
    __syncthreads();

    const int orow = tid >> 2;
    const int ocq  = (tid & 3) * 16;
    unsigned int u32s[4];
#pragma unroll
    for (int wi = 0; wi < 4; ++wi) {
        const int ro = ocq + 4 * wi;
        u32s[wi] =  (unsigned int)tile[ro + 0][orow]
                 | ((unsigned int)tile[ro + 1][orow] << 8)
                 | ((unsigned int)tile[ro + 2][orow] << 16)
                 | ((unsigned int)tile[ro + 3][orow] << 24);
    }
    uint4 o = make_uint4(u32s[0], u32s[1], u32s[2], u32s[3]);
    *reinterpret_cast<uint4*>(WqT + (size_t)(tc * 64 + orow) * RC + tr * 64 + ocq) = o;
}

// ---------------------------------------------------------------------------
// 16-element fp8 dot: w holds 16 fp8, a..d hold the 16 matching f32 x-values.
__device__ __forceinline__ float dot16(uint4 w, float4 a, float4 b, float4 c, float4 d) {
    float acc = 0.f;
    v2f f;
    f = __builtin_amdgcn_cvt_pk_f32_fp8(w.x, false); acc += f.x * a.x + f.y * a.y;
    f = __builtin_amdgcn_cvt_pk_f32_fp8(w.x, true);  acc += f.x * a.z + f.y * a.w;
    f = __builtin_amdgcn_cvt_pk_f32_fp8(w.y, false); acc += f.x * b.x + f.y * b.y;
    f = __builtin_amdgcn_cvt_pk_f32_fp8(w.y, true);  acc += f.x * b.z + f.y * b.w;
    f = __builtin_amdgcn_cvt_pk_f32_fp8(w.z, false); acc += f.x * c.x + f.y * c.y;
    f = __builtin_amdgcn_cvt_pk_f32_fp8(w.z, true);  acc += f.x * c.z + f.y * c.w;
    f = __builtin_amdgcn_cvt_pk_f32_fp8(w.w, false); acc += f.x * d.x + f.y * d.y;
    f = __builtin_amdgcn_cvt_pk_f32_fp8(w.w, true);  acc += f.x * d.z + f.y * d.w;
    return acc;
}

// Stage x (6144 floats) into padded LDS via COHERENT scalar loads (the vector
// was written by other XCDs; sc0sc1 reads need no cache invalidation).
// Scalar load f = tid + 256*k is fully coalesced per instruction.
// Padded layout: logical float4 g lives at slot g + (g>>2)  (lane byte-stride
// 80 -> bank stride 20 -> conflict-free ds_read_b128 in the matvec).
__device__ __forceinline__ void stage_x_coherent(
    const float* __restrict__ x, float* __restrict__ x_lds, int tid)
{
#pragma unroll
    for (int k = 0; k < 24; ++k) {
        const int f = tid + 256 * k;
        const int g = f >> 2, j = f & 3;
        x_lds[4 * (g + (g >> 2)) + j] = cload(x + f);
    }
}

// Two rows of W dot x (x in padded LDS). uint4 (16B) weight loads (cached —
// weights are read-only and stay warm in L2/L3 across all phases).
__device__ __forceinline__ void matvec_rows2(
    const unsigned char* __restrict__ W, const float4* __restrict__ x4,
    int rbase, int lane, float* out0, float* out1)
{
    const unsigned char* w0 = W + (size_t)rbase * RC;
    float acc0 = 0.f, acc1 = 0.f;
#pragma unroll
    for (int i = 0; i < 6; ++i) {
        const int slot = i * 320 + lane * 5;      // padded float4 slot
        const float4 a = x4[slot + 0];
        const float4 b = x4[slot + 1];
        const float4 c = x4[slot + 2];
        const float4 d = x4[slot + 3];
        const uint4 wA = *reinterpret_cast<const uint4*>(w0 +      i * 1024 + lane * 16);
        const uint4 wB = *reinterpret_cast<const uint4*>(w0 + RC + i * 1024 + lane * 16);
        acc0 += dot16(wA, a, b, c, d);
        acc1 += dot16(wB, a, b, c, d);
    }
    *out0 = wave_reduce(acc0);
    *out1 = wave_reduce(acc1);
}

// ---------------------------------------------------------------------------
// Fence-free grid barrier for a fully-resident 768-block grid.
// All data that crosses the barrier is accessed with sc0sc1 (coherent) ops,
// so NO buffer_inv / buffer_wbl2 is ever emitted and the weight working set
// stays cached. Ordering: __syncthreads() drains vmcnt(0) before s_barrier
// (compiler-guaranteed), so each block's coherent data stores are L3-visible
// before tid 0 publishes its flag.
__device__ __forceinline__ void grid_barrier(int* __restrict__ flags,
                                             int* __restrict__ gen,
                                             int bid, int tid, int g)
{
    __syncthreads();                              // drains vmcnt -> data at L3
    if (tid == 0) cstore_i(&flags[bid], g);
    if (bid == 0 && tid < 64) {
        const int base = tid * 12;                // 64 lanes x 12 = 768 flags
        for (;;) {
            bool ok = true;
#pragma unroll
            for (int k = 0; k < 12; ++k)
                ok &= (cload_i(&flags[base + k]) >= g);
            if (__all(ok)) break;
            __builtin_amdgcn_s_sleep(1);
        }
        if (tid == 0) cstore_i(gen, g);
    }
    if (tid == 0) {
        while (cload_i(gen) < g) __builtin_amdgcn_s_sleep(1);
    }
    __syncthreads();
}

// ---------------------------------------------------------------------------
// All 10 power iterations in ONE persistent kernel. 768 blocks x 256 thr;
// __launch_bounds__(256,3) -> 3 blocks/CU capacity -> all 768 co-resident.
__global__ __launch_bounds__(256, 3) void power_iter_kernel(
    const unsigned char* __restrict__ Wq, const unsigned char* __restrict__ WqT,
    const float* __restrict__ u_in, float* __restrict__ u_vec,
    float* __restrict__ v_vec, int* __restrict__ flags)
{
    __shared__ float x_lds[7680];                 // 6144 + 1536 pad floats
    float4* x4 = reinterpret_cast<float4*>(x_lds);
    int* gen = flags + NBLK;

    const int tid   = threadIdx.x;
    const int lane  = tid & 63;
    const int wid   = tid >> 6;
    const int bid   = blockIdx.x;
    const int rbase = bid * 8 + wid * 2;
    int g = 0;

    for (int it = 0; it < 10; ++it) {
        // ---- phase V: v = Wq * u ----
        stage_x_coherent(it == 0 ? u_in : u_vec, x_lds, tid);
        __syncthreads();
        float a0, a1;
        matvec_rows2(Wq, x4, rbase, lane, &a0, &a1);
        if (lane == 0) { cstore(&v_vec[rbase], a0); cstore(&v_vec[rbase + 1], a1); }
        ++g; grid_barrier(flags, gen, bid, tid, g);

        // ---- phase U: u = WqT * v * 2^-16 ----
        stage_x_coherent(v_vec, x_lds, tid);
        __syncthreads();
        matvec_rows2(WqT, x4, rbase, lane, &a0, &a1);
        if (lane == 0) {
            cstore(&u_vec[rbase],     a0 * UNSCALE);
            cstore(&u_vec[rbase + 1], a1 * UNSCALE);
        }
        if (it != 9) { ++g; grid_barrier(flags, gen, bid, tid, g); }
    }
}

// ---------------------------------------------------------------------------
// Final fp32 pass on ORIGINAL conv: t = W * (u/||u||). One block per oc.
// (Inter-kernel coherence of u_vec/v_vec is handled by the runtime's
// dispatch-boundary cache maintenance — same structure passed in round 2.)
__global__ __launch_bounds__(256) void vstep_kernel(
    const float* __restrict__ conv, const float* __restrict__ u,
    float* __restrict__ v_out)
{
    __shared__ float u_lds[RC];
    __shared__ float sred[8];
    __shared__ float sred3[12];
    __shared__ float sbcast;

    const int tid  = threadIdx.x;
    const int oc   = blockIdx.x;
    const int lane = tid & 63;
    const int wid  = tid >> 6;

    float sq = 0.f;
    const float4* u4  = reinterpret_cast<const float4*>(u);
    float4*       ul4 = reinterpret_cast<float4*>(u_lds);
#pragma unroll
    for (int k = 0; k < 6; ++k) {
        float4 q = u4[tid + 256 * k];
        ul4[tid + 256 * k] = q;
        sq += q.x * q.x + q.y * q.y + q.z * q.z + q.w * q.w;
    }
    float wsum = wave_reduce(sq);
    if (lane == 0) sred[wid] = wsum;
    __syncthreads();
    if (tid == 0) sbcast = rsqrtf(sred[0] + sred[1] + sred[2] + sred[3]);
    __syncthreads();
    const float scale = sbcast;

    float acc0 = 0.f, acc1 = 0.f, acc2 = 0.f;
    const float* base = conv + (size_t)oc * OCSTRIDE;
#pragma unroll
    for (int gi = 0; gi < 2; ++gi) {
        const int g = tid + 256 * gi;
        const float4* p4  = reinterpret_cast<const float4*>(base + g * 36);
        const float4* q12 = reinterpret_cast<const float4*>(u_lds + 12 * g);
        float uv[12];
#pragma unroll
        for (int k = 0; k < 3; ++k) {
            float4 q = q12[k];
            uv[4 * k] = q.x; uv[4 * k + 1] = q.y; uv[4 * k + 2] = q.z; uv[4 * k + 3] = q.w;
        }
#pragma unroll
        for (int j = 0; j < 9; ++j) {
            float4 q = p4[j];
            float el[4] = {q.x, q.y, q.z, q.w};
#pragma unroll
            for (int e = 0; e < 4; ++e) {
                const int m   = 4 * j + e;
                const int icl = m / 9;
                const int rem = m - 9 * icl;
                const int hh  = rem / 3;
                const int ww  = rem - 3 * hh;
                const float pv = el[e] * uv[icl * 3 + ww];
                if (hh == 0) acc0 += pv;
                else if (hh == 1) acc1 += pv;
                else acc2 += pv;
            }
        }
    }
    acc0 = wave_reduce(acc0);
    acc1 = wave_reduce(acc1);
    acc2 = wave_reduce(acc2);
    if (lane == 0) { sred3[wid] = acc0; sred3[4 + wid] = acc1; sred3[8 + wid] = acc2; }
    __syncthreads();
    if (tid < 3) {
        const float s = sred3[tid * 4 + 0] + sred3[tid * 4 + 1] +
                        sred3[tid * 4 + 2] + sred3[tid * 4 + 3];
        v_out[oc * 3 + tid] = scale * s;
    }
}

// out = 3 * dot(v,t) / ||v||   (v unnormalized iterate, t = W u_hat)
__global__ __launch_bounds__(256) void final_kernel(
    const float* __restrict__ v, const float* __restrict__ t,
    float* __restrict__ out)
{
    __shared__ float ssq[4];
    __shared__ float sdot[4];
    const int tid  = threadIdx.x;
    const int lane = tid & 63;
    const int wid  = tid >> 6;
    float sq = 0.f, dot = 0.f;
#pragma unroll
    for (int k = 0; k < 24; ++k) {
        float x = v[tid + 256 * k];
        float y = t[tid + 256 * k];
        sq  += x * x;
        dot += x * y;
    }
    sq  = wave_reduce(sq);
    dot = wave_reduce(dot);
    if (lane == 0) { ssq[wid] = sq; sdot[wid] = dot; }
    __syncthreads();
    if (tid == 0) {
        const float sqt  = ssq[0] + ssq[1] + ssq[2] + ssq[3];
        const float dott = sdot[0] + sdot[1] + sdot[2] + sdot[3];
        out[0] = 3.0f * dott * rsqrtf(sqt);
    }
}

extern "C" void kernel_launch(void* const* d_in, const int* in_sizes, int n_in,
                              void* d_out, int out_size, void* d_ws, size_t ws_size,
                              hipStream_t stream)
{
    const float* conv = (const float*)d_in[0];   // [2048,2048,3,3] fp32
    const float* u_in = (const float*)d_in[1];   // [1,6144] fp32, unit norm
    float* out = (float*)d_out;

    // ws layout: Wq fp8[6144^2] | WqT fp8[6144^2] | v_vec[6144] | u_vec[6144]
    //            | t_vec[6144] floats | flags[769] ints
    const size_t WQ_BYTES = (size_t)RC * RC;                     // 37.75 MB
    const size_t needed = 2 * WQ_BYTES + (size_t)3 * RC * sizeof(float)
                        + (NBLK + 1) * sizeof(int);
    if (ws_size < needed) return;

    unsigned char* Wq  = (unsigned char*)d_ws;
    unsigned char* WqT = Wq + WQ_BYTES;
    float* v_vec = (float*)(WqT + WQ_BYTES);
    float* u_vec = v_vec + RC;
    float* t_vec = u_vec + RC;
    int*   flags = (int*)(t_vec + RC);

    convert_q_kernel<<<RC * RC / 8 / 256, 256, 0, stream>>>(conv, Wq, flags);
    transpose_q_kernel<<<dim3(RC / 64, RC / 64), 256, 0, stream>>>(Wq, WqT);
    power_iter_kernel<<<NBLK, 256, 0, stream>>>(Wq, WqT, u_in, u_vec, v_vec, flags);

    // sigma in full fp32 from original data
    vstep_kernel<<<OC_N, 256, 0, stream>>>(conv, u_vec, t_vec);
    final_kernel<<<1, 256, 0, stream>>>(v_vec, t_vec, out);
}

// Round 5
// 862.736 us; speedup vs baseline: 1.7324x; 1.5134x over previous
//
#include <hip/hip_runtime.h>
#include <hip/hip_bf16.h>
#include <hip/hip_fp16.h>

#define OC_N     2048
#define IC_N     2048
#define RC       6144      // rows = OC_N*3, cols = IC_N*3
#define OCSTRIDE 18432     // IC_N*9 floats per oc slice
#define UNSCALE  0.0000152587890625f   // 2^-16 cancels the fp8 256x encode scale per iter
#define NBLK     768       // persistent grid: 3 blocks/CU x 256 CUs
#define NITER    10

typedef float v2f __attribute__((ext_vector_type(2)));

__device__ __forceinline__ float wave_reduce(float x) {
#pragma unroll
    for (int off = 32; off > 0; off >>= 1) x += __shfl_down(x, off, 64);
    return x;
}

// Coherent (cross-XCD, L2-bypassing) scalar access for flags and result
// publication ONLY. Bulk vector reads use plain cached loads on fresh
// (never-before-touched) buffers so they can L2-hit.
__device__ __forceinline__ void cstore(float* p, float x) {
    __hip_atomic_store(p, x, __ATOMIC_RELAXED, __HIP_MEMORY_SCOPE_AGENT);
}
__device__ __forceinline__ void cstore_i(int* p, int x) {
    __hip_atomic_store(p, x, __ATOMIC_RELAXED, __HIP_MEMORY_SCOPE_AGENT);
}
__device__ __forceinline__ int cload_i(const int* p) {
    return __hip_atomic_load(const_cast<int*>(p), __ATOMIC_RELAXED,
                             __HIP_MEMORY_SCOPE_AGENT);
}

// ---------------------------------------------------------------------------
// Wq[r][c] = fp8_e4m3(256 * conv[oc][ic][hh][ww]), r=oc*3+hh, c=ic*3+ww.
// Block 0 zeroes the grid-barrier flags with coherent stores.
__global__ __launch_bounds__(256) void convert_q_kernel(
    const float* __restrict__ conv, unsigned char* __restrict__ Wq,
    int* __restrict__ flags)
{
    if (blockIdx.x == 0) {
        for (int k = threadIdx.x; k < NBLK + 1; k += 256) cstore_i(&flags[k], 0);
    }
    const int t  = blockIdx.x * 256 + threadIdx.x;
    const int o8 = t * 8;                       // < 2^26, fits int
    const int r  = o8 / RC;
    const int c0 = o8 % RC;
    const int oc = r / 3, hh = r % 3;
    const float* base = conv + (size_t)oc * OCSTRIDE + hh * 3;
    float f[8];
#pragma unroll
    for (int e = 0; e < 8; ++e) {
        const int c  = c0 + e;
        const int ic = c / 3, ww = c - 3 * ic;
        f[e] = base[ic * 9 + ww] * 256.0f;
    }
    int lo = __builtin_amdgcn_cvt_pk_fp8_f32(f[0], f[1], 0, false);
    lo     = __builtin_amdgcn_cvt_pk_fp8_f32(f[2], f[3], lo, true);
    int hi = __builtin_amdgcn_cvt_pk_fp8_f32(f[4], f[5], 0, false);
    hi     = __builtin_amdgcn_cvt_pk_fp8_f32(f[6], f[7], hi, true);
    *reinterpret_cast<uint2*>(Wq + o8) = make_uint2((unsigned)lo, (unsigned)hi);
}

// ---------------------------------------------------------------------------
// WqT[c][r] = Wq[r][c]  — 64x64 byte tiles via LDS. Grid (96, 96), 256 thr.
__global__ __launch_bounds__(256) void transpose_q_kernel(
    const unsigned char* __restrict__ Wq, unsigned char* __restrict__ WqT)
{
    __shared__ unsigned char tile[64][68];
    const int tid = threadIdx.x;
    const int tr  = blockIdx.x;          // row tile of Wq
    const int tc  = blockIdx.y;          // col tile of Wq

    const int r  = tid >> 2;
    const int cq = (tid & 3) * 16;
    const uint4 w = *reinterpret_cast<const uint4*>(
        Wq + (size_t)(tr * 64 + r) * RC + tc * 64 + cq);
    *reinterpret_cast<unsigned int*>(&tile[r][cq +  0]) = w.x;
    *reinterpret_cast<unsigned int*>(&tile[r][cq +  4]) = w.y;
    *reinterpret_cast<unsigned int*>(&tile[r][cq +  8]) = w.z;
    *reinterpret_cast<unsigned int*>(&tile[r][cq + 12]) = w.w;
    __syncthreads();

    const int orow = tid >> 2;
    const int ocq  = (tid & 3) * 16;
    unsigned int u32s[4];
#pragma unroll
    for (int wi = 0; wi < 4; ++wi) {
        const int ro = ocq + 4 * wi;
        u32s[wi] =  (unsigned int)tile[ro + 0][orow]
                 | ((unsigned int)tile[ro + 1][orow] << 8)
                 | ((unsigned int)tile[ro + 2][orow] << 16)
                 | ((unsigned int)tile[ro + 3][orow] << 24);
    }
    uint4 o = make_uint4(u32s[0], u32s[1], u32s[2], u32s[3]);
    *reinterpret_cast<uint4*>(WqT + (size_t)(tc * 64 + orow) * RC + tr * 64 + ocq) = o;
}

// ---------------------------------------------------------------------------
// 16-element fp8 dot: w holds 16 fp8, a..d hold the 16 matching f32 x-values.
__device__ __forceinline__ float dot16(uint4 w, float4 a, float4 b, float4 c, float4 d) {
    float acc = 0.f;
    v2f f;
    f = __builtin_amdgcn_cvt_pk_f32_fp8(w.x, false); acc += f.x * a.x + f.y * a.y;
    f = __builtin_amdgcn_cvt_pk_f32_fp8(w.x, true);  acc += f.x * a.z + f.y * a.w;
    f = __builtin_amdgcn_cvt_pk_f32_fp8(w.y, false); acc += f.x * b.x + f.y * b.y;
    f = __builtin_amdgcn_cvt_pk_f32_fp8(w.y, true);  acc += f.x * b.z + f.y * b.w;
    f = __builtin_amdgcn_cvt_pk_f32_fp8(w.z, false); acc += f.x * c.x + f.y * c.y;
    f = __builtin_amdgcn_cvt_pk_f32_fp8(w.z, true);  acc += f.x * c.z + f.y * c.w;
    f = __builtin_amdgcn_cvt_pk_f32_fp8(w.w, false); acc += f.x * d.x + f.y * d.y;
    f = __builtin_amdgcn_cvt_pk_f32_fp8(w.w, true);  acc += f.x * d.z + f.y * d.w;
    return acc;
}

// Stage x (6144 floats) into padded LDS with PLAIN CACHED float4 loads.
// Safe in the persistent kernel because each phase reads a fresh buffer that
// was never touched before in this kernel (no stale L2 copy can exist); the
// first touch per XCD fills L2 and the other ~95 blocks hit it.
// Padded layout: logical float4 g -> slot g + (g>>2): lane byte-stride 80 ->
// bank stride 20 -> conflict-free ds_read_b128 in the matvec.
__device__ __forceinline__ void stage_x(const float* __restrict__ x,
                                        float4* __restrict__ x4, int tid) {
    const float4* s4 = reinterpret_cast<const float4*>(x);
#pragma unroll
    for (int k = 0; k < 6; ++k) {
        const int g = tid + 256 * k;              // logical float4 index
        x4[g + (g >> 2)] = s4[g];                 // padded slot
    }
}

// Two rows of W dot x (x in padded LDS). uint4 (16B) weight loads.
__device__ __forceinline__ void matvec_rows2(
    const unsigned char* __restrict__ W, const float4* __restrict__ x4,
    int rbase, int lane, float* out0, float* out1)
{
    const unsigned char* w0 = W + (size_t)rbase * RC;
    float acc0 = 0.f, acc1 = 0.f;
#pragma unroll
    for (int i = 0; i < 6; ++i) {
        const int slot = i * 320 + lane * 5;      // padded float4 slot
        const float4 a = x4[slot + 0];
        const float4 b = x4[slot + 1];
        const float4 c = x4[slot + 2];
        const float4 d = x4[slot + 3];
        const uint4 wA = *reinterpret_cast<const uint4*>(w0 +      i * 1024 + lane * 16);
        const uint4 wB = *reinterpret_cast<const uint4*>(w0 + RC + i * 1024 + lane * 16);
        acc0 += dot16(wA, a, b, c, d);
        acc1 += dot16(wB, a, b, c, d);
    }
    *out0 = wave_reduce(acc0);
    *out1 = wave_reduce(acc1);
}

// ---------------------------------------------------------------------------
// Grid barrier with spin backoff. Flags/gen use sc0sc1 (truly coherent) ops;
// s_sleep throttles the polling so spin traffic doesn't contend with the
// next phase's data loads at the coherence point.
__device__ __forceinline__ void grid_barrier(int* __restrict__ flags,
                                             int* __restrict__ gen,
                                             int bid, int tid, int g)
{
    __syncthreads();                              // drains vmcnt: this block's
    if (tid == 0) cstore_i(&flags[bid], g);       // coherent stores are visible
    if (bid == 0 && tid < 64) {
        const int base = tid * 12;                // 64 lanes x 12 = 768 flags
        for (;;) {
            bool ok = true;
#pragma unroll
            for (int k = 0; k < 12; ++k)
                ok &= (cload_i(&flags[base + k]) >= g);
            if (__all(ok)) break;
            __builtin_amdgcn_s_sleep(2);
        }
        if (tid == 0) cstore_i(gen, g);
    }
    if (tid == 0) {
        while (cload_i(gen) < g) __builtin_amdgcn_s_sleep(4);
    }
    __syncthreads();
}

// ---------------------------------------------------------------------------
// All 10 power iterations in ONE persistent kernel. 768 blocks x 256 thr;
// __launch_bounds__(256,3) -> 3 blocks/CU capacity -> all 768 co-resident.
// Each phase writes a FRESH ping-pong buffer (vbufs[it] / ubufs[it]) with
// coherent stores; readers use plain cached loads (no stale copy possible).
__global__ __launch_bounds__(256, 3) void power_iter_kernel(
    const unsigned char* __restrict__ Wq, const unsigned char* __restrict__ WqT,
    const float* __restrict__ u_in, float* __restrict__ vbufs,
    float* __restrict__ ubufs, int* __restrict__ flags)
{
    __shared__ float x_lds[7680];                 // 6144 + 1536 pad floats
    float4* x4 = reinterpret_cast<float4*>(x_lds);
    int* gen = flags + NBLK;

    const int tid   = threadIdx.x;
    const int lane  = tid & 63;
    const int wid   = tid >> 6;
    const int bid   = blockIdx.x;
    const int rbase = bid * 8 + wid * 2;
    int g = 0;

    for (int it = 0; it < NITER; ++it) {
        // ---- phase V: v[it] = Wq * u[it-1] ----
        const float* src = (it == 0) ? u_in : (ubufs + (size_t)(it - 1) * RC);
        stage_x(src, x4, tid);
        __syncthreads();
        float a0, a1;
        matvec_rows2(Wq, x4, rbase, lane, &a0, &a1);
        float* vout = vbufs + (size_t)it * RC;
        if (lane == 0) { cstore(&vout[rbase], a0); cstore(&vout[rbase + 1], a1); }
        ++g; grid_barrier(flags, gen, bid, tid, g);

        // ---- phase U: u[it] = WqT * v[it] * 2^-16 ----
        stage_x(vout, x4, tid);
        __syncthreads();
        matvec_rows2(WqT, x4, rbase, lane, &a0, &a1);
        float* uout = ubufs + (size_t)it * RC;
        if (lane == 0) {
            cstore(&uout[rbase],     a0 * UNSCALE);
            cstore(&uout[rbase + 1], a1 * UNSCALE);
        }
        if (it != NITER - 1) { ++g; grid_barrier(flags, gen, bid, tid, g); }
    }
}

// ---------------------------------------------------------------------------
// Final fp32 pass on ORIGINAL conv: t = W * (u/||u||). One block per oc.
__global__ __launch_bounds__(256) void vstep_kernel(
    const float* __restrict__ conv, const float* __restrict__ u,
    float* __restrict__ v_out)
{
    __shared__ float u_lds[RC];
    __shared__ float sred[8];
    __shared__ float sred3[12];
    __shared__ float sbcast;

    const int tid  = threadIdx.x;
    const int oc   = blockIdx.x;
    const int lane = tid & 63;
    const int wid  = tid >> 6;

    float sq = 0.f;
    const float4* u4  = reinterpret_cast<const float4*>(u);
    float4*       ul4 = reinterpret_cast<float4*>(u_lds);
#pragma unroll
    for (int k = 0; k < 6; ++k) {
        float4 q = u4[tid + 256 * k];
        ul4[tid + 256 * k] = q;
        sq += q.x * q.x + q.y * q.y + q.z * q.z + q.w * q.w;
    }
    float wsum = wave_reduce(sq);
    if (lane == 0) sred[wid] = wsum;
    __syncthreads();
    if (tid == 0) sbcast = rsqrtf(sred[0] + sred[1] + sred[2] + sred[3]);
    __syncthreads();
    const float scale = sbcast;

    float acc0 = 0.f, acc1 = 0.f, acc2 = 0.f;
    const float* base = conv + (size_t)oc * OCSTRIDE;
#pragma unroll
    for (int gi = 0; gi < 2; ++gi) {
        const int g = tid + 256 * gi;
        const float4* p4  = reinterpret_cast<const float4*>(base + g * 36);
        const float4* q12 = reinterpret_cast<const float4*>(u_lds + 12 * g);
        float uv[12];
#pragma unroll
        for (int k = 0; k < 3; ++k) {
            float4 q = q12[k];
            uv[4 * k] = q.x; uv[4 * k + 1] = q.y; uv[4 * k + 2] = q.z; uv[4 * k + 3] = q.w;
        }
#pragma unroll
        for (int j = 0; j < 9; ++j) {
            float4 q = p4[j];
            float el[4] = {q.x, q.y, q.z, q.w};
#pragma unroll
            for (int e = 0; e < 4; ++e) {
                const int m   = 4 * j + e;
                const int icl = m / 9;
                const int rem = m - 9 * icl;
                const int hh  = rem / 3;
                const int ww  = rem - 3 * hh;
                const float pv = el[e] * uv[icl * 3 + ww];
                if (hh == 0) acc0 += pv;
                else if (hh == 1) acc1 += pv;
                else acc2 += pv;
            }
        }
    }
    acc0 = wave_reduce(acc0);
    acc1 = wave_reduce(acc1);
    acc2 = wave_reduce(acc2);
    if (lane == 0) { sred3[wid] = acc0; sred3[4 + wid] = acc1; sred3[8 + wid] = acc2; }
    __syncthreads();
    if (tid < 3) {
        const float s = sred3[tid * 4 + 0] + sred3[tid * 4 + 1] +
                        sred3[tid * 4 + 2] + sred3[tid * 4 + 3];
        v_out[oc * 3 + tid] = scale * s;
    }
}

// out = 3 * dot(v,t) / ||v||   (v unnormalized iterate, t = W u_hat)
__global__ __launch_bounds__(256) void final_kernel(
    const float* __restrict__ v, const float* __restrict__ t,
    float* __restrict__ out)
{
    __shared__ float ssq[4];
    __shared__ float sdot[4];
    const int tid  = threadIdx.x;
    const int lane = tid & 63;
    const int wid  = tid >> 6;
    float sq = 0.f, dot = 0.f;
#pragma unroll
    for (int k = 0; k < 24; ++k) {
        float x = v[tid + 256 * k];
        float y = t[tid + 256 * k];
        sq  += x * x;
        dot += x * y;
    }
    sq  = wave_reduce(sq);
    dot = wave_reduce(dot);
    if (lane == 0) { ssq[wid] = sq; sdot[wid] = dot; }
    __syncthreads();
    if (tid == 0) {
        const float sqt  = ssq[0] + ssq[1] + ssq[2] + ssq[3];
        const float dott = sdot[0] + sdot[1] + sdot[2] + sdot[3];
        out[0] = 3.0f * dott * rsqrtf(sqt);
    }
}

extern "C" void kernel_launch(void* const* d_in, const int* in_sizes, int n_in,
                              void* d_out, int out_size, void* d_ws, size_t ws_size,
                              hipStream_t stream)
{
    const float* conv = (const float*)d_in[0];   // [2048,2048,3,3] fp32
    const float* u_in = (const float*)d_in[1];   // [1,6144] fp32, unit norm
    float* out = (float*)d_out;

    // ws layout: Wq fp8[6144^2] | WqT fp8[6144^2] | vbufs[10][6144] |
    //            ubufs[10][6144] | t_vec[6144] floats | flags[769] ints
    const size_t WQ_BYTES = (size_t)RC * RC;                     // 37.75 MB
    const size_t needed = 2 * WQ_BYTES
                        + (size_t)(2 * NITER + 1) * RC * sizeof(float)
                        + (NBLK + 1) * sizeof(int);
    if (ws_size < needed) return;

    unsigned char* Wq  = (unsigned char*)d_ws;
    unsigned char* WqT = Wq + WQ_BYTES;
    float* vbufs = (float*)(WqT + WQ_BYTES);
    float* ubufs = vbufs + (size_t)NITER * RC;
    float* t_vec = ubufs + (size_t)NITER * RC;
    int*   flags = (int*)(t_vec + RC);

    float* v_last = vbufs + (size_t)(NITER - 1) * RC;
    float* u_last = ubufs + (size_t)(NITER - 1) * RC;

    convert_q_kernel<<<RC * RC / 8 / 256, 256, 0, stream>>>(conv, Wq, flags);
    transpose_q_kernel<<<dim3(RC / 64, RC / 64), 256, 0, stream>>>(Wq, WqT);
    power_iter_kernel<<<NBLK, 256, 0, stream>>>(Wq, WqT, u_in, vbufs, ubufs, flags);

    // sigma in full fp32 from original data
    vstep_kernel<<<OC_N, 256, 0, stream>>>(conv, u_last, t_vec);
    final_kernel<<<1, 256, 0, stream>>>(v_last, t_vec, out);
}

// Round 7
// 479.518 us; speedup vs baseline: 3.1169x; 1.7992x over previous
//
#include <hip/hip_runtime.h>
#include <hip/hip_bf16.h>
#include <hip/hip_fp16.h>

#define OC_N     2048
#define IC_N     2048
#define RC       6144      // rows = OC_N*3, cols = IC_N*3
#define OCSTRIDE 18432     // IC_N*9 floats per oc slice
#define UNSCALE  0.0000152587890625f   // 2^-16 cancels the fp8 256x encode scale per iter

typedef float v2f __attribute__((ext_vector_type(2)));

__device__ __forceinline__ float wave_reduce(float x) {
#pragma unroll
    for (int off = 32; off > 0; off >>= 1) x += __shfl_down(x, off, 64);
    return x;
}

// ---------------------------------------------------------------------------
// Wq[r][c] = fp8_e4m3(256 * conv[oc][ic][hh][ww]), r=oc*3+hh, c=ic*3+ww.
// Thread writes 8 consecutive fp8 (8B store, coalesced). 18432 blocks.
__global__ __launch_bounds__(256) void convert_q_kernel(
    const float* __restrict__ conv, unsigned char* __restrict__ Wq)
{
    const int t  = blockIdx.x * 256 + threadIdx.x;
    const int o8 = t * 8;                       // < 2^26, fits int
    const int r  = o8 / RC;
    const int c0 = o8 % RC;
    const int oc = r / 3, hh = r % 3;
    const float* base = conv + (size_t)oc * OCSTRIDE + hh * 3;
    float f[8];
#pragma unroll
    for (int e = 0; e < 8; ++e) {
        const int c  = c0 + e;
        const int ic = c / 3, ww = c - 3 * ic;
        f[e] = base[ic * 9 + ww] * 256.0f;
    }
    int lo = __builtin_amdgcn_cvt_pk_fp8_f32(f[0], f[1], 0, false);
    lo     = __builtin_amdgcn_cvt_pk_fp8_f32(f[2], f[3], lo, true);
    int hi = __builtin_amdgcn_cvt_pk_fp8_f32(f[4], f[5], 0, false);
    hi     = __builtin_amdgcn_cvt_pk_fp8_f32(f[6], f[7], hi, true);
    *reinterpret_cast<uint2*>(Wq + o8) = make_uint2((unsigned)lo, (unsigned)hi);
}

// ---------------------------------------------------------------------------
// WqT[c][r] = Wq[r][c]  — 64x64 byte tiles via LDS. Grid (96, 96), 256 thr.
// LDS row stride 68 B keeps accesses to <=2-way bank conflicts.
__global__ __launch_bounds__(256) void transpose_q_kernel(
    const unsigned char* __restrict__ Wq, unsigned char* __restrict__ WqT)
{
    __shared__ unsigned char tile[64][68];
    const int tid = threadIdx.x;
    const int tr  = blockIdx.x;          // row tile of Wq
    const int tc  = blockIdx.y;          // col tile of Wq

    const int r  = tid >> 2;
    const int cq = (tid & 3) * 16;
    const uint4 w = *reinterpret_cast<const uint4*>(
        Wq + (size_t)(tr * 64 + r) * RC + tc * 64 + cq);
    *reinterpret_cast<unsigned int*>(&tile[r][cq +  0]) = w.x;
    *reinterpret_cast<unsigned int*>(&tile[r][cq +  4]) = w.y;
    *reinterpret_cast<unsigned int*>(&tile[r][cq +  8]) = w.z;
    *reinterpret_cast<unsigned int*>(&tile[r][cq + 12]) = w.w;
    __syncthreads();

    const int orow = tid >> 2;
    const int ocq  = (tid & 3) * 16;
    unsigned int u32s[4];
#pragma unroll
    for (int wi = 0; wi < 4; ++wi) {
        const int ro = ocq + 4 * wi;
        u32s[wi] =  (unsigned int)tile[ro + 0][orow]
                 | ((unsigned int)tile[ro + 1][orow] << 8)
                 | ((unsigned int)tile[ro + 2][orow] << 16)
                 | ((unsigned int)tile[ro + 3][orow] << 24);
    }
    uint4 o = make_uint4(u32s[0], u32s[1], u32s[2], u32s[3]);
    *reinterpret_cast<uint4*>(WqT + (size_t)(tc * 64 + orow) * RC + tr * 64 + ocq) = o;
}

// ---------------------------------------------------------------------------
// 16-element fp8 dot: w holds 16 fp8, a..d hold the 16 matching f32 x-values.
__device__ __forceinline__ float dot16(uint4 w, float4 a, float4 b, float4 c, float4 d) {
    float acc = 0.f;
    v2f f;
    f = __builtin_amdgcn_cvt_pk_f32_fp8(w.x, false); acc += f.x * a.x + f.y * a.y;
    f = __builtin_amdgcn_cvt_pk_f32_fp8(w.x, true);  acc += f.x * a.z + f.y * a.w;
    f = __builtin_amdgcn_cvt_pk_f32_fp8(w.y, false); acc += f.x * b.x + f.y * b.y;
    f = __builtin_amdgcn_cvt_pk_f32_fp8(w.y, true);  acc += f.x * b.z + f.y * b.w;
    f = __builtin_amdgcn_cvt_pk_f32_fp8(w.z, false); acc += f.x * c.x + f.y * c.y;
    f = __builtin_amdgcn_cvt_pk_f32_fp8(w.z, true);  acc += f.x * c.z + f.y * c.w;
    f = __builtin_amdgcn_cvt_pk_f32_fp8(w.w, false); acc += f.x * d.x + f.y * d.y;
    f = __builtin_amdgcn_cvt_pk_f32_fp8(w.w, true);  acc += f.x * d.z + f.y * d.w;
    return acc;
}

// ---------------------------------------------------------------------------
// y[r] = scale * sum_c W[r][c] * x[c].
// LDS-FREE: x (24 KB) is read directly from global with cached float4 loads
// and stays L1-resident (32 KB L1/CU); no staging, no __syncthreads.
// 1536 blocks x 256 thr = 6 blocks/CU, 24 waves/CU (2x the LDS version) for
// latency hiding of the L3-served weight stream. Wave = 1 row; per iter the
// wave reads 1 KB of weights + 4 KB of x, both contiguous/coalesced.
__global__ __launch_bounds__(256) void matvec_q_kernel(
    const unsigned char* __restrict__ W, const float* __restrict__ x,
    float* __restrict__ y, float scale)
{
    const int tid  = threadIdx.x;
    const int lane = tid & 63;
    const int wid  = tid >> 6;
    const int r    = blockIdx.x * 4 + wid;

    const unsigned char* w0 = W + (size_t)r * RC;
    const float4* x4 = reinterpret_cast<const float4*>(x);
    float acc = 0.f;
#pragma unroll
    for (int i = 0; i < 6; ++i) {
        const int c = i * 1024 + lane * 16;
        const uint4 w = *reinterpret_cast<const uint4*>(w0 + c);
        const float4 a = x4[(c >> 2) + 0];
        const float4 b = x4[(c >> 2) + 1];
        const float4 e = x4[(c >> 2) + 2];
        const float4 d = x4[(c >> 2) + 3];
        acc += dot16(w, a, b, e, d);
    }
    acc = wave_reduce(acc);
    if (lane == 0) y[r] = acc * scale;
}

// ---------------------------------------------------------------------------
// sigma = 3 * dot(v, t) / (256 * ||v|| * ||u||)
// where v = v10 (unnormalized), t = Wq * u10 (unnormalized), u = u10.
// Scale-free: the 256 divides out Wq's fp8 encode scale on t; iterate growth
// stays well inside fp32 range.
__global__ __launch_bounds__(256) void final_kernel(
    const float* __restrict__ v, const float* __restrict__ t,
    const float* __restrict__ u, float* __restrict__ out)
{
    __shared__ float ssv[4];
    __shared__ float ssu[4];
    __shared__ float sdot[4];
    const int tid  = threadIdx.x;
    const int lane = tid & 63;
    const int wid  = tid >> 6;
    float sqv = 0.f, squ = 0.f, dot = 0.f;
#pragma unroll
    for (int k = 0; k < 24; ++k) {
        const float xv = v[tid + 256 * k];
        const float xt = t[tid + 256 * k];
        const float xu = u[tid + 256 * k];
        sqv += xv * xv;
        squ += xu * xu;
        dot += xv * xt;
    }
    sqv = wave_reduce(sqv);
    squ = wave_reduce(squ);
    dot = wave_reduce(dot);
    if (lane == 0) { ssv[wid] = sqv; ssu[wid] = squ; sdot[wid] = dot; }
    __syncthreads();
    if (tid == 0) {
        const float vs = ssv[0] + ssv[1] + ssv[2] + ssv[3];
        const float us = ssu[0] + ssu[1] + ssu[2] + ssu[3];
        const float dt = sdot[0] + sdot[1] + sdot[2] + sdot[3];
        out[0] = (3.0f / 256.0f) * dt * rsqrtf(vs) * rsqrtf(us);
    }
}

extern "C" void kernel_launch(void* const* d_in, const int* in_sizes, int n_in,
                              void* d_out, int out_size, void* d_ws, size_t ws_size,
                              hipStream_t stream)
{
    const float* conv = (const float*)d_in[0];   // [2048,2048,3,3] fp32
    const float* u_in = (const float*)d_in[1];   // [1,6144] fp32, unit norm
    float* out = (float*)d_out;

    // ws layout: Wq fp8[6144^2] | WqT fp8[6144^2] | v_vec[6144] | u_vec[6144]
    //            | t_vec[6144] floats
    const size_t WQ_BYTES = (size_t)RC * RC;                     // 37.75 MB
    const size_t needed = 2 * WQ_BYTES + (size_t)3 * RC * sizeof(float);
    if (ws_size < needed) return;

    unsigned char* Wq  = (unsigned char*)d_ws;
    unsigned char* WqT = Wq + WQ_BYTES;
    float* v_vec = (float*)(WqT + WQ_BYTES);
    float* u_vec = v_vec + RC;
    float* t_vec = u_vec + RC;

    convert_q_kernel<<<RC * RC / 8 / 256, 256, 0, stream>>>(conv, Wq);
    transpose_q_kernel<<<dim3(RC / 64, RC / 64), 256, 0, stream>>>(Wq, WqT);

    for (int i = 0; i < 10; ++i) {
        matvec_q_kernel<<<RC / 4, 256, 0, stream>>>(
            Wq, (i == 0) ? u_in : u_vec, v_vec, 1.0f);
        matvec_q_kernel<<<RC / 4, 256, 0, stream>>>(
            WqT, v_vec, u_vec, UNSCALE);
    }

    // t = Wq * u10 (fp8 final pass; error ~1e-3 << 0.18 threshold)
    matvec_q_kernel<<<RC / 4, 256, 0, stream>>>(Wq, u_vec, t_vec, 1.0f);
    final_kernel<<<1, 256, 0, stream>>>(v_vec, t_vec, u_vec, out);
}